// Round 4
// baseline (1331.666 us; speedup 1.0000x reference)
//
#include <hip/hip_runtime.h>

#define NN 100000
#define NE 800000
#define HD 64
#define BK 128                            // nodes per bucket
#define NBUCK ((NN + BK - 1) / BK)        // 782
#define PA_EPT 16                         // edges per thread in passA
#define PA_NB ((NE + 256 * PA_EPT - 1) / (256 * PA_EPT))   // 196

__device__ __forceinline__ int load_idx(const void* ei, int i, bool is32) {
    if (is32) return ((const int*)ei)[i];
    return (int)(((const long long*)ei)[i]);
}

// zero flag + bucket counters
__global__ void k_init(int* bcnt, int* flag) {
    int t = threadIdx.x;
    if (t < NBUCK) bcnt[t] = 0;
    if (t == NBUCK) *flag = 0;
}

// detect int32 vs int64: one block checks the first 4096 int64 slots.
// int64 node ids are all in [0,NN); if the buffer is really int32, a slot is
// two packed random ids -> out of range with overwhelming probability.
__global__ void k_detect(const void* ei, int* flag) {
    __shared__ int bad;
    if (threadIdx.x == 0) bad = 0;
    __syncthreads();
    const long long* p = (const long long*)ei;
    for (int i = threadIdx.x; i < 4096; i += 1024) {
        long long v = p[i];
        if (v < 0 || v >= (long long)NN) bad = 1;
    }
    __syncthreads();
    if (threadIdx.x == 0 && bad) *flag = 1;
}

// global bucket histogram via per-block LDS histograms
__global__ __launch_bounds__(256) void k_pass0(const void* ei, const int* flag,
                                               int* bcnt) {
    __shared__ int h[NBUCK];
    for (int i = threadIdx.x; i < NBUCK; i += 256) h[i] = 0;
    __syncthreads();
    bool is32 = (*flag != 0);
    int stride = gridDim.x * 256;
    for (int e = blockIdx.x * 256 + threadIdx.x; e < NE; e += stride) {
        int dst = load_idx(ei, NE + e, is32);
        atomicAdd(&h[dst >> 7], 1);
    }
    __syncthreads();
    for (int i = threadIdx.x; i < NBUCK; i += 256) {
        int v = h[i];
        if (v) atomicAdd(&bcnt[i], v);
    }
}

// scan 782 bucket counts -> offs[0..NBUCK], curs[b]=offs[b]
__global__ __launch_bounds__(256) void k_scan1(const int* __restrict__ bcnt,
                                               int* __restrict__ offs,
                                               int* __restrict__ curs) {
    __shared__ int sc[256];
    int t = threadIdx.x;
    int v[4], s = 0;
#pragma unroll
    for (int i = 0; i < 4; ++i) {
        int b = t * 4 + i;
        v[i] = (b < NBUCK) ? bcnt[b] : 0;
        s += v[i];
    }
    sc[t] = s;
    __syncthreads();
    for (int off = 1; off < 256; off <<= 1) {
        int add = (t >= off) ? sc[t - off] : 0;
        __syncthreads();
        sc[t] += add;
        __syncthreads();
    }
    int run = sc[t] - s;   // exclusive prefix
#pragma unroll
    for (int i = 0; i < 4; ++i) {
        int b = t * 4 + i;
        if (b < NBUCK) { offs[b] = run; curs[b] = run; }
        run += v[i];
    }
    if (t == 255) offs[NBUCK] = sc[255];
}

// bin edges into bucket-major array; packed word = src | (dst&127)<<17
__global__ __launch_bounds__(256) void k_passA(const void* ei, const int* flag,
                                               int* curs, unsigned* ebuf) {
    __shared__ int h[NBUCK];
    __shared__ int base[NBUCK];
    for (int i = threadIdx.x; i < NBUCK; i += 256) h[i] = 0;
    __syncthreads();
    bool is32 = (*flag != 0);
    int e0 = blockIdx.x * (256 * PA_EPT);
    int src[PA_EPT], dst[PA_EPT];
#pragma unroll
    for (int i = 0; i < PA_EPT; ++i) {
        int e = e0 + i * 256 + threadIdx.x;
        if (e < NE) {
            src[i] = load_idx(ei, e, is32);
            dst[i] = load_idx(ei, NE + e, is32);
            atomicAdd(&h[dst[i] >> 7], 1);
        } else dst[i] = -1;
    }
    __syncthreads();
    for (int i = threadIdx.x; i < NBUCK; i += 256) {
        int v = h[i];
        base[i] = v ? atomicAdd(&curs[i], v) : 0;
        h[i] = 0;                      // reuse as local rank counter
    }
    __syncthreads();
#pragma unroll
    for (int i = 0; i < PA_EPT; ++i) {
        if (dst[i] >= 0) {
            int b = dst[i] >> 7;
            int p = base[b] + atomicAdd(&h[b], 1);
            ebuf[p] = (unsigned)src[i] | ((unsigned)(dst[i] & 127) << 17);
        }
    }
}

// per-bucket degree histogram -> dinv (no global atomics)
__global__ __launch_bounds__(256) void k_deg(const unsigned* __restrict__ ebuf,
                                             const int* __restrict__ offs,
                                             float* __restrict__ dinv) {
    __shared__ int cnt[BK];
    int bk = blockIdx.x;
    if (threadIdx.x < BK) cnt[threadIdx.x] = 0;
    __syncthreads();
    int rs = offs[bk], re = offs[bk + 1];
    for (int i = rs + threadIdx.x; i < re; i += 256)
        atomicAdd(&cnt[ebuf[i] >> 17], 1);
    __syncthreads();
    if (threadIdx.x < BK) {
        int node = bk * BK + threadIdx.x;
        if (node < NN) dinv[node] = rsqrtf((float)(cnt[threadIdx.x] + 1));
    }
}

// H[n x 64] = X[n x 64] @ W[64 x 64]; optional bias; optional row-prescale by
// dinv (Hs = dinv[r] * (X@W)[r]) so aggregation needs no per-edge dinv load.
template <bool BIAS, bool PRE>
__global__ __launch_bounds__(256) void k_gemm(const float* __restrict__ X,
                                              const float* __restrict__ W,
                                              const float* __restrict__ bias,
                                              const float* __restrict__ dinv,
                                              float* __restrict__ H, int n) {
    __shared__ float Ws[64 * 64];
    __shared__ float Xs[32 * 64];
    int t = threadIdx.x;
    for (int i = t; i < 64 * 64; i += 256) Ws[i] = W[i];
    int row0 = blockIdx.x * 32;
    for (int i = t; i < 32 * 64; i += 256) {
        int r = row0 + (i >> 6);
        Xs[i] = (r < n) ? X[r * 64 + (i & 63)] : 0.f;
    }
    __syncthreads();
    int c = t & 63, rq = t >> 6;
    float acc[8];
#pragma unroll
    for (int rr = 0; rr < 8; ++rr) acc[rr] = 0.f;
    for (int k = 0; k < 64; ++k) {
        float w = Ws[k * 64 + c];
#pragma unroll
        for (int rr = 0; rr < 8; ++rr)
            acc[rr] += Xs[(rq * 8 + rr) * 64 + k] * w;
    }
    float bv = BIAS ? bias[c] : 0.f;
#pragma unroll
    for (int rr = 0; rr < 8; ++rr) {
        int r = row0 + rq * 8 + rr;
        if (r < n) {
            float v = acc[rr] + bv;
            if (PRE) v *= dinv[r];
            H[r * 64 + c] = v;
        }
    }
}

// bucket aggregation: LDS acc[128 x 64]; waves stream 64-edge batches
// (lane-held packed words + shfl), gather Hs rows coalesced, ds_add into LDS.
// out[n] = relu( dinv[n]*(sum_e Hs[src] + Hs[n]) + b )
__global__ __launch_bounds__(256) void k_bagg(const float* __restrict__ Hs,
                                              const int* __restrict__ offs,
                                              const unsigned* __restrict__ ebuf,
                                              const float* __restrict__ dinv,
                                              const float* __restrict__ bias,
                                              float* __restrict__ out) {
    __shared__ float acc[BK * HD];            // 32 KB -> 5 blocks/CU
    int t = threadIdx.x;
    float4* a4 = (float4*)acc;
    for (int i = t; i < BK * HD / 4; i += 256) a4[i] = make_float4(0.f, 0.f, 0.f, 0.f);
    __syncthreads();
    int bk = blockIdx.x;
    int rs = offs[bk], re = offs[bk + 1];
    int lane = t & 63, w = t >> 6;
    for (int b0 = rs + w * 64; b0 < re; b0 += 256) {
        int n = re - b0; if (n > 64) n = 64;
        unsigned wd = (lane < n) ? ebuf[b0 + lane] : 0u;
        int j = 0;
        for (; j + 4 <= n; j += 4) {
            unsigned w0 = __shfl(wd, j), w1 = __shfl(wd, j + 1),
                     w2 = __shfl(wd, j + 2), w3 = __shfl(wd, j + 3);
            float v0 = Hs[(w0 & 0x1FFFFu) * HD + lane];
            float v1 = Hs[(w1 & 0x1FFFFu) * HD + lane];
            float v2 = Hs[(w2 & 0x1FFFFu) * HD + lane];
            float v3 = Hs[(w3 & 0x1FFFFu) * HD + lane];
            atomicAdd(&acc[(w0 >> 17) * HD + lane], v0);
            atomicAdd(&acc[(w1 >> 17) * HD + lane], v1);
            atomicAdd(&acc[(w2 >> 17) * HD + lane], v2);
            atomicAdd(&acc[(w3 >> 17) * HD + lane], v3);
        }
        for (; j < n; ++j) {
            unsigned w0 = __shfl(wd, j);
            atomicAdd(&acc[(w0 >> 17) * HD + lane], Hs[(w0 & 0x1FFFFu) * HD + lane]);
        }
    }
    __syncthreads();
    float bv = bias[lane];
    for (int r = w; r < BK; r += 4) {
        int node = bk * BK + r;
        if (node >= NN) break;
        float dv = dinv[node];
        float v = dv * (acc[r * HD + lane] + Hs[node * HD + lane]) + bv;
        out[node * HD + lane] = fmaxf(v, 0.f);
    }
}

extern "C" void kernel_launch(void* const* d_in, const int* in_sizes, int n_in,
                              void* d_out, int out_size, void* d_ws, size_t ws_size,
                              hipStream_t stream) {
    const float* x  = (const float*)d_in[0];
    const void*  ei = d_in[1];               // edge_index, dtype detected on device
    const float* W0 = (const float*)d_in[3];
    const float* b0 = (const float*)d_in[4];
    const float* W1 = (const float*)d_in[5];
    const float* b1 = (const float*)d_in[6];
    const float* W2 = (const float*)d_in[7];
    const float* b2 = (const float*)d_in[8];
    const float* Wl = (const float*)d_in[9];
    const float* bl = (const float*)d_in[10];

    char* ws = (char*)d_ws;
    int*      flag = (int*)(ws);
    int*      bcnt = (int*)(ws + 256);
    int*      offs = (int*)(ws + 4352);          // 783 ints
    int*      curs = (int*)(ws + 8448);          // 782 ints
    float*    dinv = (float*)(ws + 12544);       // 400000 B
    unsigned* ebuf = (unsigned*)(ws + 412672);   // 3.2 MB (+slack)

    float* out0 = (float*)d_out;             // first output (layer-3 relu)
    float* out1 = out0 + (size_t)NN * HD;    // second output; also Hs scratch

    int gG = NN / 32;                        // 3125 gemm blocks

    // ---- preprocessing: bucket counting sort + degrees ----
    k_init<<<1, 1024, 0, stream>>>(bcnt, flag);
    k_detect<<<1, 1024, 0, stream>>>(ei, flag);
    k_pass0<<<128, 256, 0, stream>>>(ei, flag, bcnt);
    k_scan1<<<1, 256, 0, stream>>>(bcnt, offs, curs);
    k_passA<<<PA_NB, 256, 0, stream>>>(ei, flag, curs, ebuf);
    k_deg<<<NBUCK, 256, 0, stream>>>(ebuf, offs, dinv);

    // ---- layer 0 ----
    k_gemm<false, true><<<gG, 256, 0, stream>>>(x, W0, nullptr, dinv, out1, NN);
    k_bagg<<<NBUCK, 256, 0, stream>>>(out1, offs, ebuf, dinv, b0, out0);
    // ---- layer 1 ----
    k_gemm<false, true><<<gG, 256, 0, stream>>>(out0, W1, nullptr, dinv, out1, NN);
    k_bagg<<<NBUCK, 256, 0, stream>>>(out1, offs, ebuf, dinv, b1, out0);
    // ---- layer 2 ----
    k_gemm<false, true><<<gG, 256, 0, stream>>>(out0, W2, nullptr, dinv, out1, NN);
    k_bagg<<<NBUCK, 256, 0, stream>>>(out1, offs, ebuf, dinv, b2, out0);
    // ---- final linear ----
    k_gemm<true, false><<<gG, 256, 0, stream>>>(out0, Wl, bl, nullptr, out1, NN);
}

// Round 5
// 392.551 us; speedup vs baseline: 3.3923x; 3.3923x over previous
//
#include <hip/hip_runtime.h>

#define NN 100000
#define NE 800000
#define HD 64
#define BK 128                            // nodes per bucket
#define NBUCK ((NN + BK - 1) / BK)        // 782
#define PA_EPT 16                         // edges per thread in passA
#define PA_NB ((NE + 256 * PA_EPT - 1) / (256 * PA_EPT))   // 196

__device__ __forceinline__ int load_idx(const void* ei, int i, bool is32) {
    if (is32) return ((const int*)ei)[i];
    return (int)(((const long long*)ei)[i]);
}

// zero flag + bucket counters
__global__ void k_init(int* bcnt, int* flag) {
    int t = threadIdx.x;
    if (t < NBUCK) bcnt[t] = 0;
    if (t == NBUCK) *flag = 0;
}

// detect int32 vs int64: one block checks the first 4096 int64 slots.
__global__ void k_detect(const void* ei, int* flag) {
    __shared__ int bad;
    if (threadIdx.x == 0) bad = 0;
    __syncthreads();
    const long long* p = (const long long*)ei;
    for (int i = threadIdx.x; i < 4096; i += 1024) {
        long long v = p[i];
        if (v < 0 || v >= (long long)NN) bad = 1;
    }
    __syncthreads();
    if (threadIdx.x == 0 && bad) *flag = 1;
}

// global bucket histogram via per-block LDS histograms
__global__ __launch_bounds__(256) void k_pass0(const void* ei, const int* flag,
                                               int* bcnt) {
    __shared__ int h[NBUCK];
    for (int i = threadIdx.x; i < NBUCK; i += 256) h[i] = 0;
    __syncthreads();
    bool is32 = (*flag != 0);
    int stride = gridDim.x * 256;
    for (int e = blockIdx.x * 256 + threadIdx.x; e < NE; e += stride) {
        int dst = load_idx(ei, NE + e, is32);
        atomicAdd(&h[dst >> 7], 1);
    }
    __syncthreads();
    for (int i = threadIdx.x; i < NBUCK; i += 256) {
        int v = h[i];
        if (v) atomicAdd(&bcnt[i], v);
    }
}

// scan 782 bucket counts -> offs[0..NBUCK], curs[b]=offs[b]
__global__ __launch_bounds__(256) void k_scan1(const int* __restrict__ bcnt,
                                               int* __restrict__ offs,
                                               int* __restrict__ curs) {
    __shared__ int sc[256];
    int t = threadIdx.x;
    int v[4], s = 0;
#pragma unroll
    for (int i = 0; i < 4; ++i) {
        int b = t * 4 + i;
        v[i] = (b < NBUCK) ? bcnt[b] : 0;
        s += v[i];
    }
    sc[t] = s;
    __syncthreads();
    for (int off = 1; off < 256; off <<= 1) {
        int add = (t >= off) ? sc[t - off] : 0;
        __syncthreads();
        sc[t] += add;
        __syncthreads();
    }
    int run = sc[t] - s;   // exclusive prefix
#pragma unroll
    for (int i = 0; i < 4; ++i) {
        int b = t * 4 + i;
        if (b < NBUCK) { offs[b] = run; curs[b] = run; }
        run += v[i];
    }
    if (t == 255) offs[NBUCK] = sc[255];
}

// bin edges into bucket-major ebuf; packed word = src | (dst&127)<<17
__global__ __launch_bounds__(256) void k_passA(const void* ei, const int* flag,
                                               int* curs, unsigned* ebuf) {
    __shared__ int h[NBUCK];
    __shared__ int base[NBUCK];
    for (int i = threadIdx.x; i < NBUCK; i += 256) h[i] = 0;
    __syncthreads();
    bool is32 = (*flag != 0);
    int e0 = blockIdx.x * (256 * PA_EPT);
    int src[PA_EPT], dst[PA_EPT];
#pragma unroll
    for (int i = 0; i < PA_EPT; ++i) {
        int e = e0 + i * 256 + threadIdx.x;
        if (e < NE) {
            src[i] = load_idx(ei, e, is32);
            dst[i] = load_idx(ei, NE + e, is32);
            atomicAdd(&h[dst[i] >> 7], 1);
        } else dst[i] = -1;
    }
    __syncthreads();
    for (int i = threadIdx.x; i < NBUCK; i += 256) {
        int v = h[i];
        base[i] = v ? atomicAdd(&curs[i], v) : 0;
        h[i] = 0;                      // reuse as local rank counter
    }
    __syncthreads();
#pragma unroll
    for (int i = 0; i < PA_EPT; ++i) {
        if (dst[i] >= 0) {
            int b = dst[i] >> 7;
            int p = base[b] + atomicAdd(&h[b], 1);
            ebuf[p] = (unsigned)src[i] | ((unsigned)(dst[i] & 127) << 17);
        }
    }
}

// per-bucket counting sort -> per-node CSR (noffs, csr_src) + dinv.
// All histogram/scan/rank work in LDS; writes land in the bucket's contiguous
// run (~4 KB) so no global write amplification, no global atomics.
__global__ __launch_bounds__(256) void k_passB(const unsigned* __restrict__ ebuf,
                                               const int* __restrict__ offs,
                                               int* __restrict__ noffs,
                                               int* __restrict__ csr_src,
                                               float* __restrict__ dinv) {
    __shared__ int cnt[BK];
    __shared__ int sc[BK];
    __shared__ int nbase[BK];
    __shared__ int rank[BK];
    int bk = blockIdx.x;
    int t = threadIdx.x;
    if (t < BK) { cnt[t] = 0; rank[t] = 0; }
    __syncthreads();
    int rs = offs[bk], re = offs[bk + 1];
    for (int i = rs + t; i < re; i += 256)
        atomicAdd(&cnt[ebuf[i] >> 17], 1);
    __syncthreads();
    if (t < BK) sc[t] = cnt[t];
    __syncthreads();
    for (int off = 1; off < BK; off <<= 1) {       // inclusive scan of cnt
        int v = 0;
        if (t < BK && t >= off) v = sc[t - off];
        __syncthreads();
        if (t < BK) sc[t] += v;
        __syncthreads();
    }
    if (t < BK) {
        int node = bk * BK + t;
        int nb = rs + sc[t] - cnt[t];              // exclusive prefix
        nbase[t] = nb;
        if (node < NN) {
            noffs[node] = nb;
            dinv[node] = rsqrtf((float)(cnt[t] + 1));
        }
    }
    if (bk == NBUCK - 1 && t == 0) noffs[NN] = re;
    __syncthreads();
    for (int i = rs + t; i < re; i += 256) {
        unsigned w = ebuf[i];
        int dl = w >> 17;
        int p = nbase[dl] + atomicAdd(&rank[dl], 1);
        csr_src[p] = (int)(w & 0x1FFFFu);
    }
}

// H[n x 64] = X[n x 64] @ W[64 x 64]; optional bias; optional row-prescale by
// dinv (Hs = dinv[r] * (X@W)[r]) so aggregation needs no per-edge dinv load.
template <bool BIAS, bool PRE>
__global__ __launch_bounds__(256) void k_gemm(const float* __restrict__ X,
                                              const float* __restrict__ W,
                                              const float* __restrict__ bias,
                                              const float* __restrict__ dinv,
                                              float* __restrict__ H, int n) {
    __shared__ float Ws[64 * 64];
    __shared__ float Xs[32 * 64];
    int t = threadIdx.x;
    for (int i = t; i < 64 * 64; i += 256) Ws[i] = W[i];
    int row0 = blockIdx.x * 32;
    for (int i = t; i < 32 * 64; i += 256) {
        int r = row0 + (i >> 6);
        Xs[i] = (r < n) ? X[r * 64 + (i & 63)] : 0.f;
    }
    __syncthreads();
    int c = t & 63, rq = t >> 6;
    float acc[8];
#pragma unroll
    for (int rr = 0; rr < 8; ++rr) acc[rr] = 0.f;
    for (int k = 0; k < 64; ++k) {
        float w = Ws[k * 64 + c];
#pragma unroll
        for (int rr = 0; rr < 8; ++rr)
            acc[rr] += Xs[(rq * 8 + rr) * 64 + k] * w;
    }
    float bv = BIAS ? bias[c] : 0.f;
#pragma unroll
    for (int rr = 0; rr < 8; ++rr) {
        int r = row0 + rq * 8 + rr;
        if (r < n) {
            float v = acc[rr] + bv;
            if (PRE) v *= dinv[r];
            H[r * 64 + c] = v;
        }
    }
}

// Aggregation (R3 structure, 2x unrolled): wave = 1 node; 4 groups of 16
// lanes; group g walks edges e0+g, e0+g+4, ... loading prescaled rows as
// float4 (16 lanes x 16 B); 2 rows in flight per group = 8 per wave.
// out[n] = relu( dinv[n]*(sum_e Hs[src] + Hs[n]) + b )
__global__ __launch_bounds__(256) void k_agg(const float4* __restrict__ Hs4,
                                             const int* __restrict__ noffs,
                                             const int* __restrict__ csr_src,
                                             const float* __restrict__ dinv,
                                             const float4* __restrict__ b4,
                                             float4* __restrict__ out4) {
    int node = blockIdx.x * 4 + (threadIdx.x >> 6);
    if (node >= NN) return;
    int lane = threadIdx.x & 63;
    int g = lane >> 4;          // edge group 0..3
    int q = lane & 15;          // float4 chunk within the 64-feature row
    float dv = dinv[node];

    float4 acc = make_float4(0.f, 0.f, 0.f, 0.f);
    if (g == 0) acc = Hs4[(size_t)node * 16 + q];   // self-loop (prescaled)
    int e0 = noffs[node], e1 = noffs[node + 1];
    int e = e0 + g;
    for (; e + 4 < e1; e += 8) {
        int s0 = csr_src[e], s1 = csr_src[e + 4];
        float4 h0 = Hs4[(size_t)s0 * 16 + q];
        float4 h1 = Hs4[(size_t)s1 * 16 + q];
        acc.x += h0.x + h1.x; acc.y += h0.y + h1.y;
        acc.z += h0.z + h1.z; acc.w += h0.w + h1.w;
    }
    if (e < e1) {
        int s = csr_src[e];
        float4 h = Hs4[(size_t)s * 16 + q];
        acc.x += h.x; acc.y += h.y; acc.z += h.z; acc.w += h.w;
    }
#pragma unroll
    for (int off = 16; off < 64; off <<= 1) {
        acc.x += __shfl_xor(acc.x, off, 64);
        acc.y += __shfl_xor(acc.y, off, 64);
        acc.z += __shfl_xor(acc.z, off, 64);
        acc.w += __shfl_xor(acc.w, off, 64);
    }
    if (g == 0) {
        float4 bv = b4[q];
        float4 r;
        r.x = fmaxf(acc.x * dv + bv.x, 0.f);
        r.y = fmaxf(acc.y * dv + bv.y, 0.f);
        r.z = fmaxf(acc.z * dv + bv.z, 0.f);
        r.w = fmaxf(acc.w * dv + bv.w, 0.f);
        out4[(size_t)node * 16 + q] = r;
    }
}

extern "C" void kernel_launch(void* const* d_in, const int* in_sizes, int n_in,
                              void* d_out, int out_size, void* d_ws, size_t ws_size,
                              hipStream_t stream) {
    const float* x  = (const float*)d_in[0];
    const void*  ei = d_in[1];               // edge_index, dtype detected on device
    const float* W0 = (const float*)d_in[3];
    const float* b0 = (const float*)d_in[4];
    const float* W1 = (const float*)d_in[5];
    const float* b1 = (const float*)d_in[6];
    const float* W2 = (const float*)d_in[7];
    const float* b2 = (const float*)d_in[8];
    const float* Wl = (const float*)d_in[9];
    const float* bl = (const float*)d_in[10];

    char* ws = (char*)d_ws;
    int*      flag    = (int*)(ws);
    int*      bcnt    = (int*)(ws + 256);
    int*      offs    = (int*)(ws + 4352);        // 783 ints
    int*      curs    = (int*)(ws + 8448);        // 782 ints
    float*    dinv    = (float*)(ws + 12544);     // 400000 B
    int*      noffs   = (int*)(ws + 412672);      // 100001 ints
    int*      csr_src = (int*)(ws + 812800);      // 3.2 MB

    float* out0 = (float*)d_out;             // first output (layer-3 relu)
    float* out1 = out0 + (size_t)NN * HD;    // second output; Hs scratch
    unsigned* ebuf = (unsigned*)out1;        // bucket-major edges; dies before GEMM0

    int gG = NN / 32;                        // 3125 gemm blocks
    int gA = (NN + 3) / 4;                   // 25000 agg blocks

    // ---- preprocessing: bucket bin + in-bucket counting sort -> CSR ----
    k_init<<<1, 1024, 0, stream>>>(bcnt, flag);
    k_detect<<<1, 1024, 0, stream>>>(ei, flag);
    k_pass0<<<128, 256, 0, stream>>>(ei, flag, bcnt);
    k_scan1<<<1, 256, 0, stream>>>(bcnt, offs, curs);
    k_passA<<<PA_NB, 256, 0, stream>>>(ei, flag, curs, ebuf);
    k_passB<<<NBUCK, 256, 0, stream>>>(ebuf, offs, noffs, csr_src, dinv);

    // ---- layer 0 ----
    k_gemm<false, true><<<gG, 256, 0, stream>>>(x, W0, nullptr, dinv, out1, NN);
    k_agg<<<gA, 256, 0, stream>>>((const float4*)out1, noffs, csr_src, dinv,
                                  (const float4*)b0, (float4*)out0);
    // ---- layer 1 ----
    k_gemm<false, true><<<gG, 256, 0, stream>>>(out0, W1, nullptr, dinv, out1, NN);
    k_agg<<<gA, 256, 0, stream>>>((const float4*)out1, noffs, csr_src, dinv,
                                  (const float4*)b1, (float4*)out0);
    // ---- layer 2 ----
    k_gemm<false, true><<<gG, 256, 0, stream>>>(out0, W2, nullptr, dinv, out1, NN);
    k_agg<<<gA, 256, 0, stream>>>((const float4*)out1, noffs, csr_src, dinv,
                                  (const float4*)b2, (float4*)out0);
    // ---- final linear ----
    k_gemm<true, false><<<gG, 256, 0, stream>>>(out0, Wl, bl, nullptr, out1, NN);
}